// Round 1
// baseline (1011.310 us; speedup 1.0000x reference)
//
#include <hip/hip_runtime.h>
#include <math.h>

#define NEURONS 64
#define HID 32
#define GD 103

// ---------------------------------------------------------------------------
// k_gpart: gpart[b][h] = b1[h] + sum_d gf[b][d] * W1[(64+d)][h]
// ---------------------------------------------------------------------------
__global__ __launch_bounds__(256) void k_gpart(
    const float* __restrict__ gf, const float* __restrict__ W1,
    const float* __restrict__ b1, float* __restrict__ gpart, int B)
{
    int t = blockIdx.x * 256 + threadIdx.x;
    if (t >= B * HID) return;
    int b = t >> 5;
    int h = t & 31;
    float acc = b1[h];
    const float* grow = gf + (size_t)b * GD;
    for (int d = 0; d < GD; ++d)
        acc = fmaf(grow[d], W1[(NEURONS + d) * HID + h], acc);
    gpart[t] = acc;
}

// ---------------------------------------------------------------------------
// k_bounds: start[b] = lower_bound(node_batch, b); start[B] = N
// node_batch is sorted ascending.
// ---------------------------------------------------------------------------
__global__ __launch_bounds__(256) void k_bounds(
    const int* __restrict__ nb, int* __restrict__ start, int n, int B)
{
    int b = blockIdx.x * 256 + threadIdx.x;
    if (b > B) return;
    if (b == B) { start[B] = n; return; }
    int lo = 0, hi = n;
    while (lo < hi) {
        int mid = (lo + hi) >> 1;
        if (nb[mid] < b) lo = mid + 1; else hi = mid;
    }
    start[b] = lo;
}

// ---------------------------------------------------------------------------
// k_logits: per node i:
//   acc[h] = gpart[seg][h] + sum_{d<64} x[i][d]*W1[d][h]
//   logit  = b2 + sum_h W2[h]*softplus(acc[h])
// W1/W2 indexed uniformly -> compiler emits s_load + v_fmac with SGPR operand.
// ---------------------------------------------------------------------------
__global__ __launch_bounds__(256) void k_logits(
    const float* __restrict__ x, const int* __restrict__ nb,
    const float* __restrict__ gpart, const float* __restrict__ W1,
    const float* __restrict__ W2, const float* __restrict__ b2,
    float* __restrict__ logits, int n)
{
    int i = blockIdx.x * 256 + threadIdx.x;
    if (i >= n) return;

    int seg = nb[i];

    // init accumulators with per-graph partial
    float acc[HID];
    const float4* gp = (const float4*)(gpart + (size_t)seg * HID);
    #pragma unroll
    for (int q = 0; q < HID / 4; ++q) {
        float4 v = gp[q];
        acc[4 * q + 0] = v.x; acc[4 * q + 1] = v.y;
        acc[4 * q + 2] = v.z; acc[4 * q + 3] = v.w;
    }

    // load this node's 64 features
    float xv[NEURONS];
    const float4* xr = (const float4*)(x + (size_t)i * NEURONS);
    #pragma unroll
    for (int q = 0; q < NEURONS / 4; ++q) {
        float4 v = xr[q];
        xv[4 * q + 0] = v.x; xv[4 * q + 1] = v.y;
        xv[4 * q + 2] = v.z; xv[4 * q + 3] = v.w;
    }

    // 64x32 FMA block; W1 uniform -> scalar loads
    #pragma unroll
    for (int d = 0; d < NEURONS; ++d) {
        float xd = xv[d];
        #pragma unroll
        for (int h = 0; h < HID; ++h)
            acc[h] = fmaf(xd, W1[d * HID + h], acc[h]);
    }

    // softplus + W2 reduction
    float logit = b2[0];
    #pragma unroll
    for (int h = 0; h < HID; ++h) {
        float z = acc[h];
        float sp = fmaxf(z, 0.0f) + log1pf(__expf(-fabsf(z)));
        logit = fmaf(sp, W2[h], logit);
    }
    logits[i] = logit;
}

// ---------------------------------------------------------------------------
// k_seg: one block per segment; max then sum(exp(l-m)); store m, 1/sum
// ---------------------------------------------------------------------------
__device__ inline float wave_max(float v) {
    #pragma unroll
    for (int o = 32; o > 0; o >>= 1) v = fmaxf(v, __shfl_down(v, o, 64));
    return v;
}
__device__ inline float wave_sum(float v) {
    #pragma unroll
    for (int o = 32; o > 0; o >>= 1) v += __shfl_down(v, o, 64);
    return v;
}

__global__ __launch_bounds__(256) void k_seg(
    const float* __restrict__ logits, const int* __restrict__ start,
    float* __restrict__ segm, float* __restrict__ seginv)
{
    int b = blockIdx.x;
    int s = start[b], e = start[b + 1];
    int tid = threadIdx.x;
    int wid = tid >> 6;

    __shared__ float sm[4];

    float m = -INFINITY;
    for (int i = s + tid; i < e; i += 256) m = fmaxf(m, logits[i]);
    m = wave_max(m);
    if ((tid & 63) == 0) sm[wid] = m;
    __syncthreads();
    float bm = fmaxf(fmaxf(sm[0], sm[1]), fmaxf(sm[2], sm[3]));
    __syncthreads();

    float sum = 0.0f;
    for (int i = s + tid; i < e; i += 256) sum += __expf(logits[i] - bm);
    sum = wave_sum(sum);
    if ((tid & 63) == 0) sm[wid] = sum;
    __syncthreads();
    if (tid == 0) {
        float tot = sm[0] + sm[1] + sm[2] + sm[3];
        segm[b] = bm;
        seginv[b] = 1.0f / tot;
    }
}

// ---------------------------------------------------------------------------
// k_out: out[i] = exp(logits[i] - m[seg]) * inv_sum[seg]
// ---------------------------------------------------------------------------
__global__ __launch_bounds__(256) void k_out(
    const float* __restrict__ logits, const int* __restrict__ nb,
    const float* __restrict__ segm, const float* __restrict__ seginv,
    float* __restrict__ out, int n)
{
    int i = blockIdx.x * 256 + threadIdx.x;
    if (i >= n) return;
    int seg = nb[i];
    out[i] = __expf(logits[i] - segm[seg]) * seginv[seg];
}

// ---------------------------------------------------------------------------
extern "C" void kernel_launch(void* const* d_in, const int* in_sizes, int n_in,
                              void* d_out, int out_size, void* d_ws, size_t ws_size,
                              hipStream_t stream)
{
    const float* x   = (const float*)d_in[0];
    const int*   nb  = (const int*)d_in[1];
    const float* gf  = (const float*)d_in[2];
    const float* W1  = (const float*)d_in[3];
    const float* b1  = (const float*)d_in[4];
    const float* W2  = (const float*)d_in[5];
    const float* b2  = (const float*)d_in[6];
    float* out = (float*)d_out;

    const int N = in_sizes[1];
    const int B = in_sizes[2] / GD;

    // workspace layout
    float* gpart  = (float*)d_ws;              // B*HID floats
    float* logits = gpart + (size_t)B * HID;   // N floats
    int*   start  = (int*)(logits + N);        // B+1 ints
    float* segm   = (float*)(start + B + 1);   // B floats
    float* seginv = segm + B;                  // B floats

    int gp_blocks = (B * HID + 255) / 256;
    k_gpart<<<gp_blocks, 256, 0, stream>>>(gf, W1, b1, gpart, B);

    int bd_blocks = (B + 1 + 255) / 256;
    k_bounds<<<bd_blocks, 256, 0, stream>>>(nb, start, N, B);

    int n_blocks = (N + 255) / 256;
    k_logits<<<n_blocks, 256, 0, stream>>>(x, nb, gpart, W1, W2, b2, logits, N);

    k_seg<<<B, 256, 0, stream>>>(logits, start, segm, seginv);

    k_out<<<n_blocks, 256, 0, stream>>>(logits, nb, segm, seginv, out, N);
}

// Round 2
// 981.916 us; speedup vs baseline: 1.0299x; 1.0299x over previous
//
#include <hip/hip_runtime.h>
#include <math.h>

#define NEURONS 64
#define HID 32
#define GD 103

// ---------------------------------------------------------------------------
// k_gpart: gpart[b][h] = b1[h] + sum_d gf[b][d] * W1[(64+d)][h]
// ---------------------------------------------------------------------------
__global__ __launch_bounds__(256) void k_gpart(
    const float* __restrict__ gf, const float* __restrict__ W1,
    const float* __restrict__ b1, float* __restrict__ gpart, int B)
{
    int t = blockIdx.x * 256 + threadIdx.x;
    if (t >= B * HID) return;
    int b = t >> 5;
    int h = t & 31;
    float acc = b1[h];
    const float* grow = gf + (size_t)b * GD;
    for (int d = 0; d < GD; ++d)
        acc = fmaf(grow[d], W1[(NEURONS + d) * HID + h], acc);
    gpart[t] = acc;
}

// ---------------------------------------------------------------------------
// k_bounds: start[b] = lower_bound(node_batch, b); start[B] = N
// ---------------------------------------------------------------------------
__global__ __launch_bounds__(256) void k_bounds(
    const int* __restrict__ nb, int* __restrict__ start, int n, int B)
{
    int b = blockIdx.x * 256 + threadIdx.x;
    if (b > B) return;
    if (b == B) { start[B] = n; return; }
    int lo = 0, hi = n;
    while (lo < hi) {
        int mid = (lo + hi) >> 1;
        if (nb[mid] < b) lo = mid + 1; else hi = mid;
    }
    start[b] = lo;
}

// ---------------------------------------------------------------------------
// k_logits — single-pass streaming GEMV.
// d-loop kept ROLLED (#pragma unroll 1) with a manual cur/nxt double-buffer:
// prevents the register allocator from rematerializing x loads and re-reading
// x 3x from HBM (R1: VGPR=28, FETCH=1.5GB). acc[32] must stay live across the
// rolled loop -> single pass over x guaranteed.
// ---------------------------------------------------------------------------
__device__ __forceinline__ void fma_rows4(float acc[HID], float4 c,
                                          const float* __restrict__ w)
{
    #pragma unroll
    for (int h = 0; h < HID; ++h) acc[h] = fmaf(c.x, w[h], acc[h]);
    #pragma unroll
    for (int h = 0; h < HID; ++h) acc[h] = fmaf(c.y, w[HID + h], acc[h]);
    #pragma unroll
    for (int h = 0; h < HID; ++h) acc[h] = fmaf(c.z, w[2 * HID + h], acc[h]);
    #pragma unroll
    for (int h = 0; h < HID; ++h) acc[h] = fmaf(c.w, w[3 * HID + h], acc[h]);
}

__global__ __launch_bounds__(256) void k_logits(
    const float* __restrict__ x, const int* __restrict__ nb,
    const float* __restrict__ gpart, const float* __restrict__ W1,
    const float* __restrict__ W2, const float* __restrict__ b2,
    float* __restrict__ logits, int n)
{
    int i = blockIdx.x * 256 + threadIdx.x;
    if (i >= n) return;

    int seg = nb[i];

    float acc[HID];
    const float4* gp = (const float4*)(gpart + (size_t)seg * HID);
    #pragma unroll
    for (int q = 0; q < HID / 4; ++q) {
        float4 v = gp[q];
        acc[4 * q + 0] = v.x; acc[4 * q + 1] = v.y;
        acc[4 * q + 2] = v.z; acc[4 * q + 3] = v.w;
    }

    const float4* xr = (const float4*)(x + (size_t)i * NEURONS);
    float4 cur = xr[0];
    #pragma unroll 1
    for (int q = 0; q < NEURONS / 4 - 1; ++q) {
        float4 nxt = xr[q + 1];
        fma_rows4(acc, cur, W1 + q * 4 * HID);
        cur = nxt;
    }
    fma_rows4(acc, cur, W1 + (NEURONS - 4) * HID);

    // softplus via native exp/log: sp = max(z,0) + log(1 + exp(-|z|))
    float logit = b2[0];
    #pragma unroll
    for (int h = 0; h < HID; ++h) {
        float z = acc[h];
        float sp = fmaxf(z, 0.0f) + __logf(1.0f + __expf(-fabsf(z)));
        logit = fmaf(sp, W2[h], logit);
    }
    logits[i] = logit;
}

// ---------------------------------------------------------------------------
// k_seg: one block per segment. Segment nodes are CONTIGUOUS (sorted nb), so
// the same block computes max, sum(exp), and writes the normalized weights.
// ---------------------------------------------------------------------------
__device__ __forceinline__ float wave_max(float v) {
    #pragma unroll
    for (int o = 32; o > 0; o >>= 1) v = fmaxf(v, __shfl_down(v, o, 64));
    return v;
}
__device__ __forceinline__ float wave_sum(float v) {
    #pragma unroll
    for (int o = 32; o > 0; o >>= 1) v += __shfl_down(v, o, 64);
    return v;
}

__global__ __launch_bounds__(256) void k_seg(
    const float* __restrict__ logits, const int* __restrict__ start,
    float* __restrict__ out)
{
    int b = blockIdx.x;
    int s = start[b], e = start[b + 1];
    int tid = threadIdx.x;
    int wid = tid >> 6;

    __shared__ float sm[4];

    float m = -INFINITY;
    for (int i = s + tid; i < e; i += 256) m = fmaxf(m, logits[i]);
    m = wave_max(m);
    if ((tid & 63) == 0) sm[wid] = m;
    __syncthreads();
    float bm = fmaxf(fmaxf(sm[0], sm[1]), fmaxf(sm[2], sm[3]));
    __syncthreads();

    float sum = 0.0f;
    for (int i = s + tid; i < e; i += 256) sum += __expf(logits[i] - bm);
    sum = wave_sum(sum);
    if ((tid & 63) == 0) sm[wid] = sum;
    __syncthreads();
    float inv = 1.0f / (sm[0] + sm[1] + sm[2] + sm[3]);

    for (int i = s + tid; i < e; i += 256)
        out[i] = __expf(logits[i] - bm) * inv;
}

// ---------------------------------------------------------------------------
extern "C" void kernel_launch(void* const* d_in, const int* in_sizes, int n_in,
                              void* d_out, int out_size, void* d_ws, size_t ws_size,
                              hipStream_t stream)
{
    const float* x   = (const float*)d_in[0];
    const int*   nb  = (const int*)d_in[1];
    const float* gf  = (const float*)d_in[2];
    const float* W1  = (const float*)d_in[3];
    const float* b1  = (const float*)d_in[4];
    const float* W2  = (const float*)d_in[5];
    const float* b2  = (const float*)d_in[6];
    float* out = (float*)d_out;

    const int N = in_sizes[1];
    const int B = in_sizes[2] / GD;

    float* gpart  = (float*)d_ws;              // B*HID floats
    float* logits = gpart + (size_t)B * HID;   // N floats
    int*   start  = (int*)(logits + N);        // B+1 ints

    int gp_blocks = (B * HID + 255) / 256;
    k_gpart<<<gp_blocks, 256, 0, stream>>>(gf, W1, b1, gpart, B);

    int bd_blocks = (B + 1 + 255) / 256;
    k_bounds<<<bd_blocks, 256, 0, stream>>>(nb, start, N, B);

    int n_blocks = (N + 255) / 256;
    k_logits<<<n_blocks, 256, 0, stream>>>(x, nb, gpart, W1, W2, b2, logits, N);

    k_seg<<<B, 256, 0, stream>>>(logits, start, out);
}

// Round 3
// 732.324 us; speedup vs baseline: 1.3810x; 1.3408x over previous
//
#include <hip/hip_runtime.h>
#include <math.h>

#define NEURONS 64
#define HID 32
#define GD 103
#define TW 16          // columns per chunk
#define NCHUNK (NEURONS / TW)
#define PAD 17         // LDS row stride (floats); 17 is odd -> conflict-free
#define ROWS 256       // rows per block

// ---------------------------------------------------------------------------
// k_gpart: gpart[b][h] = b1[h] + sum_d gf[b][d] * W1[(64+d)][h]
// ---------------------------------------------------------------------------
__global__ __launch_bounds__(256) void k_gpart(
    const float* __restrict__ gf, const float* __restrict__ W1,
    const float* __restrict__ b1, float* __restrict__ gpart, int B)
{
    int t = blockIdx.x * 256 + threadIdx.x;
    if (t >= B * HID) return;
    int b = t >> 5;
    int h = t & 31;
    float acc = b1[h];
    const float* grow = gf + (size_t)b * GD;
    for (int d = 0; d < GD; ++d)
        acc = fmaf(grow[d], W1[(NEURONS + d) * HID + h], acc);
    gpart[t] = acc;
}

// ---------------------------------------------------------------------------
// k_bounds: start[b] = lower_bound(node_batch, b); start[B] = N
// ---------------------------------------------------------------------------
__global__ __launch_bounds__(256) void k_bounds(
    const int* __restrict__ nb, int* __restrict__ start, int n, int B)
{
    int b = blockIdx.x * 256 + threadIdx.x;
    if (b > B) return;
    if (b == B) { start[B] = n; return; }
    int lo = 0, hi = n;
    while (lo < hi) {
        int mid = (lo + hi) >> 1;
        if (nb[mid] < b) lo = mid + 1; else hi = mid;
    }
    start[b] = lo;
}

// ---------------------------------------------------------------------------
// k_logits — LDS-staged streaming GEMV.
// Block = 256 threads = 256 rows. 4 column-chunks of 16 floats; each chunk is
// cooperatively staged into LDS (coalesced float4 global loads), then each
// thread FMAs its own row against W1 (uniform -> SGPR operands).
// The __syncthreads() inside the chunk loop makes loop fission (the R1/R2
// "re-read x 3x to save registers" pathology, FETCH=1.5GB) impossible.
// LDS row stride 17 floats: odd stride -> all-bank permutation, no conflicts.
// ---------------------------------------------------------------------------
__global__ __launch_bounds__(256) void k_logits(
    const float* __restrict__ x, const int* __restrict__ nb,
    const float* __restrict__ gpart, const float* __restrict__ W1,
    const float* __restrict__ W2, const float* __restrict__ b2,
    float* __restrict__ logits, int n)
{
    __shared__ float xs[2][ROWS * PAD];

    const int tid = threadIdx.x;
    const long base = (long)blockIdx.x * ROWS;
    const long i = base + tid;
    const bool alive = i < (long)n;

    int seg = alive ? nb[i] : 0;

    float acc[HID];
    const float4* gp = (const float4*)(gpart + (size_t)seg * HID);
    #pragma unroll
    for (int q = 0; q < HID / 4; ++q) {
        float4 v = gp[q];
        acc[4 * q + 0] = v.x; acc[4 * q + 1] = v.y;
        acc[4 * q + 2] = v.z; acc[4 * q + 3] = v.w;
    }

    // prefetch chunk 0: piece p = tid + 256k covers row p>>2, quarter p&3
    float4 pre[4];
    #pragma unroll
    for (int k = 0; k < 4; ++k) {
        int p = tid + 256 * k;
        long r = base + (p >> 2);
        if (r >= n) r = n - 1;
        pre[k] = *(const float4*)(x + r * NEURONS + (p & 3) * 4);
    }

    for (int c = 0; c < NCHUNK; ++c) {
        // write prefetched chunk into LDS buffer c&1
        float* buf = xs[c & 1];
        #pragma unroll
        for (int k = 0; k < 4; ++k) {
            int p = tid + 256 * k;
            float* dst = buf + (p >> 2) * PAD + (p & 3) * 4;
            dst[0] = pre[k].x; dst[1] = pre[k].y;
            dst[2] = pre[k].z; dst[3] = pre[k].w;
        }
        __syncthreads();

        // prefetch next chunk (global -> regs, no LDS hazard)
        if (c < NCHUNK - 1) {
            #pragma unroll
            for (int k = 0; k < 4; ++k) {
                int p = tid + 256 * k;
                long r = base + (p >> 2);
                if (r >= n) r = n - 1;
                pre[k] = *(const float4*)(x + r * NEURONS + (c + 1) * TW + (p & 3) * 4);
            }
        }

        // compute this chunk: 16 d x 32 h FMAs, x from LDS, W1 uniform
        const float* xrow = xs[c & 1] + tid * PAD;
        const float* w = W1 + c * TW * HID;
        #pragma unroll
        for (int d = 0; d < TW; ++d) {
            float xd = xrow[d];
            #pragma unroll
            for (int h = 0; h < HID; ++h)
                acc[h] = fmaf(xd, w[d * HID + h], acc[h]);
        }
        __syncthreads();
    }

    if (!alive) return;

    // softplus via native exp/log, then W2 reduction
    float logit = b2[0];
    #pragma unroll
    for (int h = 0; h < HID; ++h) {
        float z = acc[h];
        float sp = fmaxf(z, 0.0f) + __logf(1.0f + __expf(-fabsf(z)));
        logit = fmaf(sp, W2[h], logit);
    }
    logits[i] = logit;
}

// ---------------------------------------------------------------------------
// k_seg: one block per segment (nodes contiguous): max, sum(exp), normalize.
// ---------------------------------------------------------------------------
__device__ __forceinline__ float wave_max(float v) {
    #pragma unroll
    for (int o = 32; o > 0; o >>= 1) v = fmaxf(v, __shfl_down(v, o, 64));
    return v;
}
__device__ __forceinline__ float wave_sum(float v) {
    #pragma unroll
    for (int o = 32; o > 0; o >>= 1) v += __shfl_down(v, o, 64);
    return v;
}

__global__ __launch_bounds__(256) void k_seg(
    const float* __restrict__ logits, const int* __restrict__ start,
    float* __restrict__ out)
{
    int b = blockIdx.x;
    int s = start[b], e = start[b + 1];
    int tid = threadIdx.x;
    int wid = tid >> 6;

    __shared__ float sm[4];

    float m = -INFINITY;
    for (int i = s + tid; i < e; i += 256) m = fmaxf(m, logits[i]);
    m = wave_max(m);
    if ((tid & 63) == 0) sm[wid] = m;
    __syncthreads();
    float bm = fmaxf(fmaxf(sm[0], sm[1]), fmaxf(sm[2], sm[3]));
    __syncthreads();

    float sum = 0.0f;
    for (int i = s + tid; i < e; i += 256) sum += __expf(logits[i] - bm);
    sum = wave_sum(sum);
    if ((tid & 63) == 0) sm[wid] = sum;
    __syncthreads();
    float inv = 1.0f / (sm[0] + sm[1] + sm[2] + sm[3]);

    for (int i = s + tid; i < e; i += 256)
        out[i] = __expf(logits[i] - bm) * inv;
}

// ---------------------------------------------------------------------------
extern "C" void kernel_launch(void* const* d_in, const int* in_sizes, int n_in,
                              void* d_out, int out_size, void* d_ws, size_t ws_size,
                              hipStream_t stream)
{
    const float* x   = (const float*)d_in[0];
    const int*   nb  = (const int*)d_in[1];
    const float* gf  = (const float*)d_in[2];
    const float* W1  = (const float*)d_in[3];
    const float* b1  = (const float*)d_in[4];
    const float* W2  = (const float*)d_in[5];
    const float* b2  = (const float*)d_in[6];
    float* out = (float*)d_out;

    const int N = in_sizes[1];
    const int B = in_sizes[2] / GD;

    float* gpart  = (float*)d_ws;              // B*HID floats
    float* logits = gpart + (size_t)B * HID;   // N floats
    int*   start  = (int*)(logits + N);        // B+1 ints

    int gp_blocks = (B * HID + 255) / 256;
    k_gpart<<<gp_blocks, 256, 0, stream>>>(gf, W1, b1, gpart, B);

    int bd_blocks = (B + 1 + 255) / 256;
    k_bounds<<<bd_blocks, 256, 0, stream>>>(nb, start, N, B);

    int n_blocks = (N + ROWS - 1) / ROWS;
    k_logits<<<n_blocks, 256, 0, stream>>>(x, nb, gpart, W1, W2, b2, logits, N);

    k_seg<<<B, 256, 0, stream>>>(logits, start, out);
}